// Round 2
// baseline (7920.605 us; speedup 1.0000x reference)
//
#include <hip/hip_runtime.h>
#include <hip/hip_bf16.h>

typedef __bf16 bf16_t;
typedef __bf16 bf16x8 __attribute__((ext_vector_type(8)));
typedef __bf16 bf16x4 __attribute__((ext_vector_type(4)));
typedef float f32x4 __attribute__((ext_vector_type(4)));

#define DEVI static __device__ __forceinline__

DEVI f32x4 mfma16(bf16x8 a, bf16x8 b, f32x4 c) {
  return __builtin_amdgcn_mfma_f32_16x16x32_bf16(a, b, c, 0, 0, 0);
}

DEVI float sigf(float x) { return 1.f / (1.f + __expf(-x)); }
DEVI float tanh_fast(float x) { return 2.f / (1.f + __expf(-2.f * x)) - 1.f; }

// ---------------------------------------------------------------------------
// Pre-swizzle weight matrix W [K,N] (f32 row-major) into B-fragment-major bf16:
// Wsw[kc][nt][lane][j] = W[kc*32 + (lane>>4)*8 + j][nt*16 + (lane&15)]
// ---------------------------------------------------------------------------
__global__ __launch_bounds__(256) void k_prep(const float* __restrict__ src,
                                              bf16_t* __restrict__ dst,
                                              int K, int N) {
  int gid = blockIdx.x * 256 + threadIdx.x;
  int total = (K / 32) * (N / 16) * 64;
  if (gid >= total) return;
  int l = gid & 63;
  int fi = gid >> 6;
  int NT = N >> 4;
  int nt = fi % NT;
  int kc = fi / NT;
  int row0 = kc * 32 + (l >> 4) * 8;
  int col = nt * 16 + (l & 15);
  bf16x8 v;
#pragma unroll
  for (int j = 0; j < 8; ++j) v[j] = (bf16_t)src[(size_t)(row0 + j) * N + col];
  *(bf16x8*)(dst + (size_t)gid * 8) = v;
}

// ---------------------------------------------------------------------------
// Input projection: xg[t] = x[:, t_eff, :] @ Wx + b  for one direction.
// Output xg in C-fragment-major layout:
//   xg[((t*8 + mtg)*128 + ntg)*64 + lane][r]  (bf16, r=0..3)
// ---------------------------------------------------------------------------
template <int KDIM>
__global__ __launch_bounds__(256) void k_proj(const float* __restrict__ x, int T,
                                              int dir,
                                              const bf16_t* __restrict__ Wsw,
                                              const float* __restrict__ bias,
                                              bf16_t* __restrict__ xg) {
  int chunk = blockIdx.x & 7;
  int t = blockIdx.x >> 3;
  int tt = dir ? (T - 1 - t) : t;
  int tid = threadIdx.x;
  int l = tid & 63, w = tid >> 6;
  int wr = w >> 1, wc = w & 1;
  int rl = l & 15, kl = (l >> 4) * 8;
  f32x4 acc[4][8];
#pragma unroll
  for (int mt = 0; mt < 4; ++mt)
#pragma unroll
    for (int nt = 0; nt < 8; ++nt) acc[mt][nt] = f32x4{0.f, 0.f, 0.f, 0.f};

  for (int kc = 0; kc < KDIM / 32; ++kc) {
    bf16x8 a[4];
#pragma unroll
    for (int mt = 0; mt < 4; ++mt) {
      int chain = wr * 64 + mt * 16 + rl;
      const float* p = x + ((size_t)chain * T + tt) * KDIM + kc * 32 + kl;
      float4 u = *(const float4*)p;
      float4 v = *(const float4*)(p + 4);
      bf16x8 av;
      av[0] = (bf16_t)u.x; av[1] = (bf16_t)u.y; av[2] = (bf16_t)u.z; av[3] = (bf16_t)u.w;
      av[4] = (bf16_t)v.x; av[5] = (bf16_t)v.y; av[6] = (bf16_t)v.z; av[7] = (bf16_t)v.w;
      a[mt] = av;
    }
#pragma unroll
    for (int nt = 0; nt < 8; ++nt) {
      int nt_g = chunk * 16 + wc * 8 + nt;
      bf16x8 b = *(const bf16x8*)(Wsw + ((size_t)(kc * 128 + nt_g) * 64 + l) * 8);
#pragma unroll
      for (int mt = 0; mt < 4; ++mt) acc[mt][nt] = mfma16(a[mt], b, acc[mt][nt]);
    }
  }

#pragma unroll
  for (int mt = 0; mt < 4; ++mt) {
    int mt_g = wr * 4 + mt;
#pragma unroll
    for (int nt = 0; nt < 8; ++nt) {
      int nt_g = chunk * 16 + wc * 8 + nt;
      float bv = bias[nt_g * 16 + rl];
      bf16x4 ov;
#pragma unroll
      for (int r = 0; r < 4; ++r) ov[r] = (bf16_t)(acc[mt][nt][r] + bv);
      *(bf16x4*)(xg + (((size_t)(t * 8 + mt_g) * 128 + nt_g) * 64 + l) * 4) = ov;
    }
  }
}

// ---------------------------------------------------------------------------
// Persistent recurrence kernel. Grid: 128 WGs x 256 threads (one WG per CU,
// all co-resident: VGPR-bound 1 WG/CU, 128 <= 256 CUs -> no deadlock).
// Wave (species, dir, mb, jt): owns 32 chains (mb quarter) x 16 hidden cols
// (jt tile) = gate cols {g*512 + jt*16 .. +16} for g=0..3.
// Wh slice (64 B-fragments = 256 VGPRs) loaded ONCE, held in registers.
// h exchanged per step via global in A-fragment-major layout; per-group
// (species,dir,mb = 32 waves) flag barrier with release/acquire atomics.
// h layout per (species,dir,parity): [kc=16][mtg=8][lane=64][j=8] bf16 (128KB)
// ---------------------------------------------------------------------------
__global__ __launch_bounds__(256, 1) void k_rnn(
    const bf16_t* __restrict__ xg_vid, const bf16_t* __restrict__ xg_txt,
    const bf16_t* __restrict__ Wh_vid, const bf16_t* __restrict__ Wh_txt,
    bf16_t* __restrict__ hfrag, int* __restrict__ flags,
    bf16_t* __restrict__ feats) {
  int bid = blockIdx.x;
  int species = bid >> 6;      // 0 = vid, 1 = txt
  int dir = (bid >> 5) & 1;
  int r5 = bid & 31;
  int tid = threadIdx.x;
  int w = tid >> 6, l = tid & 63;
  int widx = r5 * 4 + w;       // 0..127 within (species,dir)
  int mb = widx >> 5;          // chain quarter 0..3
  int jt = widx & 31;          // hidden col tile 0..31
  int rl = l & 15, lh = l >> 4;

  int NT = species ? 64 : 256;
  const bf16_t* xg = (species ? xg_txt : xg_vid) + (size_t)dir * NT * (128 * 2048);
  const bf16_t* Wh = (species ? Wh_txt : Wh_vid) + (size_t)dir * (512 * 2048);
  bf16_t* hf = hfrag + (size_t)(species * 2 + dir) * 2 * 65536;
  int grp = (species * 2 + dir) * 4 + mb;
  int* flg = flags + grp * 256;
  int colbase = species * 1024 + dir * 512;

  // Preload Wh slice into registers: B[kc][g], fully static indexing.
  bf16x8 B[16][4];
#pragma unroll
  for (int kc = 0; kc < 16; ++kc)
#pragma unroll
    for (int g = 0; g < 4; ++g)
      B[kc][g] = *(const bf16x8*)(Wh + ((size_t)(kc * 128 + g * 32 + jt) * 64 + l) * 8);

  float c[2][4];
#pragma unroll
  for (int mt = 0; mt < 2; ++mt)
#pragma unroll
    for (int r = 0; r < 4; ++r) c[mt][r] = 0.f;

  // h-write address components (hidden col j = jt*16 + rl)
  int kc_w = jt >> 1;
  int p = (jt & 1) * 16 + rl;   // j & 31
  int lp = (p >> 3) * 16;       // + row -> lane index in frag
  int jp = p & 7;

  for (int s = 0; s < NT; ++s) {
    // Issue xg loads early (independent of h).
    bf16x4 xv[2][4];
#pragma unroll
    for (int mt = 0; mt < 2; ++mt)
#pragma unroll
      for (int g = 0; g < 4; ++g)
        xv[mt][g] = *(const bf16x4*)(
            xg + (((size_t)(s * 8 + mb * 2 + mt) * 128 + g * 32 + jt) * 64 + l) * 4);

    if (s > 0) {
      const int* fl = flg + (s - 1);
      while (__hip_atomic_load(fl, __ATOMIC_ACQUIRE, __HIP_MEMORY_SCOPE_AGENT) < 32)
        __builtin_amdgcn_s_sleep(2);
    }

    f32x4 acc[2][4];
#pragma unroll
    for (int mt = 0; mt < 2; ++mt)
#pragma unroll
      for (int g = 0; g < 4; ++g)
        acc[mt][g] = f32x4{(float)xv[mt][g][0], (float)xv[mt][g][1],
                           (float)xv[mt][g][2], (float)xv[mt][g][3]};

    if (s > 0) {
      const bf16_t* hcur = hf + (size_t)(s & 1) * 65536;
#pragma unroll
      for (int kc = 0; kc < 16; ++kc) {
        bf16x8 a[2];
#pragma unroll
        for (int mt = 0; mt < 2; ++mt)
          a[mt] = *(const bf16x8*)(hcur + ((size_t)(kc * 8 + mb * 2 + mt) * 64 + l) * 8);
#pragma unroll
        for (int g = 0; g < 4; ++g)
#pragma unroll
          for (int mt = 0; mt < 2; ++mt)
            acc[mt][g] = mfma16(a[mt], B[kc][g], acc[mt][g]);
      }
    }

    bf16_t* hnext = hf + (size_t)((s + 1) & 1) * 65536;
#pragma unroll
    for (int mt = 0; mt < 2; ++mt) {
      int mtg = mb * 2 + mt;
#pragma unroll
      for (int r = 0; r < 4; ++r) {
        float iv = acc[mt][0][r], fv = acc[mt][1][r];
        float gv = acc[mt][2][r], ov = acc[mt][3][r];
        float cn = sigf(fv) * c[mt][r] + sigf(iv) * tanh_fast(gv);
        c[mt][r] = cn;
        float hn = sigf(ov) * tanh_fast(cn);
        int row = lh * 4 + r;
        hnext[((size_t)(kc_w * 8 + mtg) * 64 + (lp + row)) * 8 + jp] = (bf16_t)hn;
        if (s == NT - 1) {
          int chain = mb * 32 + mt * 16 + row;
          feats[(size_t)chain * 2048 + colbase + jt * 16 + rl] = (bf16_t)hn;
        }
      }
    }
    __threadfence();
    if (l == 0)
      __hip_atomic_fetch_add(flg + s, 1, __ATOMIC_RELEASE, __HIP_MEMORY_SCOPE_AGENT);
  }
}

// ---------------------------------------------------------------------------
// h1[mlp] = relu(feats @ W1[mlp] + b1[mlp]) : [128,2048]x[2048,512]
// ---------------------------------------------------------------------------
__global__ __launch_bounds__(256) void k_mlp(const bf16_t* __restrict__ feats,
                                             const bf16_t* __restrict__ W1sw,
                                             const float* __restrict__ sqb1,
                                             const float* __restrict__ rqb1,
                                             float* __restrict__ h1) {
  int mlp = blockIdx.x >> 3, chunk = blockIdx.x & 7;
  const bf16_t* Wsw = W1sw + (size_t)mlp * (2048 * 512);
  const float* b1 = mlp ? rqb1 : sqb1;
  int tid = threadIdx.x;
  int l = tid & 63, w = tid >> 6;
  int rl = l & 15, kl = (l >> 4) * 8;
  f32x4 acc[2][4];
#pragma unroll
  for (int mt = 0; mt < 2; ++mt)
#pragma unroll
    for (int nt = 0; nt < 4; ++nt) acc[mt][nt] = f32x4{0.f, 0.f, 0.f, 0.f};

  for (int kc = 0; kc < 64; ++kc) {
    bf16x8 a[2];
#pragma unroll
    for (int mt = 0; mt < 2; ++mt) {
      int row = w * 32 + mt * 16 + rl;
      a[mt] = *(const bf16x8*)(feats + (size_t)row * 2048 + kc * 32 + kl);
    }
#pragma unroll
    for (int nt = 0; nt < 4; ++nt) {
      int nt_g = chunk * 4 + nt;
      bf16x8 b = *(const bf16x8*)(Wsw + ((size_t)(kc * 32 + nt_g) * 64 + l) * 8);
#pragma unroll
      for (int mt = 0; mt < 2; ++mt) acc[mt][nt] = mfma16(a[mt], b, acc[mt][nt]);
    }
  }

#pragma unroll
  for (int mt = 0; mt < 2; ++mt)
#pragma unroll
    for (int nt = 0; nt < 4; ++nt) {
      int col = (chunk * 4 + nt) * 16 + rl;
      float bv = b1[col];
#pragma unroll
      for (int r = 0; r < 4; ++r) {
        int row = w * 32 + mt * 16 + (l >> 4) * 4 + r;
        float v = acc[mt][nt][r] + bv;
        h1[(size_t)mlp * (128 * 512) + (size_t)row * 512 + col] = v > 0.f ? v : 0.f;
      }
    }
}

// ---------------------------------------------------------------------------
__global__ __launch_bounds__(256) void k_final(const float* __restrict__ h1,
                                               const float* __restrict__ sqW2,
                                               const float* __restrict__ sqb2,
                                               const float* __restrict__ rqW2,
                                               const float* __restrict__ rqb2,
                                               const int* __restrict__ labels,
                                               float* __restrict__ out) {
  __shared__ float sc[128][2];
  int tid = threadIdx.x;
  int row = tid >> 1, m = tid & 1;
  const float* hp = h1 + ((size_t)m * 128 + row) * 512;
  const float* w2 = m ? rqW2 : sqW2;
  float s = m ? *rqb2 : *sqb2;
  for (int k = 0; k < 512; ++k) s += hp[k] * w2[k];
  sc[row][m] = s;
  __syncthreads();
  if (tid < 16) {
    float acc = 0.f;
    for (int i = 0; i < 8; ++i) {
      int r = tid * 8 + i;
      acc += (labels[r] <= 3) ? sc[r][0] : sc[r][1];
    }
    acc *= (1.f / 8.f);
    out[tid] = 1.f / (1.f + __expf(-acc));
  }
}

// ---------------------------------------------------------------------------
extern "C" void kernel_launch(void* const* d_in, const int* in_sizes, int n_in,
                              void* d_out, int out_size, void* d_ws, size_t ws_size,
                              hipStream_t stream) {
  const float* vid  = (const float*)d_in[0];
  const float* txt  = (const float*)d_in[1];
  const int* labels = (const int*)d_in[2];
  const float* vWxf = (const float*)d_in[3];
  const float* vWhf = (const float*)d_in[4];
  const float* vbf  = (const float*)d_in[5];
  const float* vWxb = (const float*)d_in[6];
  const float* vWhb = (const float*)d_in[7];
  const float* vbb  = (const float*)d_in[8];
  const float* tWxf = (const float*)d_in[9];
  const float* tWhf = (const float*)d_in[10];
  const float* tbf  = (const float*)d_in[11];
  const float* tWxb = (const float*)d_in[12];
  const float* tWhb = (const float*)d_in[13];
  const float* tbb  = (const float*)d_in[14];
  const float* sqW1 = (const float*)d_in[15];
  const float* sqb1 = (const float*)d_in[16];
  const float* sqW2 = (const float*)d_in[17];
  const float* sqb2 = (const float*)d_in[18];
  const float* rqW1 = (const float*)d_in[19];
  const float* rqb1 = (const float*)d_in[20];
  const float* rqW2 = (const float*)d_in[21];
  const float* rqb2 = (const float*)d_in[22];

  char* p = (char*)d_ws;
  auto alloc = [&](size_t bytes) {
    char* r = p;
    p += (bytes + 255) & ~(size_t)255;
    return r;
  };
  bf16_t* vWxf_sw = (bf16_t*)alloc((size_t)1024 * 2048 * 2);
  bf16_t* vWxb_sw = (bf16_t*)alloc((size_t)1024 * 2048 * 2);
  bf16_t* vWh_sw  = (bf16_t*)alloc((size_t)2 * 512 * 2048 * 2);  // [dir]
  bf16_t* tWxf_sw = (bf16_t*)alloc((size_t)512 * 2048 * 2);
  bf16_t* tWxb_sw = (bf16_t*)alloc((size_t)512 * 2048 * 2);
  bf16_t* tWh_sw  = (bf16_t*)alloc((size_t)2 * 512 * 2048 * 2);  // [dir]
  bf16_t* W1_sw   = (bf16_t*)alloc((size_t)2 * 2048 * 512 * 2);  // [mlp]
  bf16_t* xg_vid  = (bf16_t*)alloc((size_t)2 * 256 * 128 * 2048 * 2);
  bf16_t* xg_txt  = (bf16_t*)alloc((size_t)2 * 64 * 128 * 2048 * 2);
  bf16_t* hfrag   = (bf16_t*)alloc((size_t)4 * 2 * 65536 * 2);   // [sp*dir][parity]
  int*    flags   = (int*)alloc((size_t)16 * 256 * 4);
  bf16_t* feats   = (bf16_t*)alloc((size_t)128 * 2048 * 2);
  float*  h1      = (float*)alloc((size_t)2 * 128 * 512 * 4);
  (void)ws_size; (void)in_sizes; (void)n_in; (void)out_size;

  auto prep = [&](const float* s, bf16_t* d, int K, int N) {
    int total = (K / 32) * (N / 16) * 64;
    k_prep<<<(total + 255) / 256, 256, 0, stream>>>(s, d, K, N);
  };
  prep(vWxf, vWxf_sw, 1024, 2048);
  prep(vWxb, vWxb_sw, 1024, 2048);
  prep(vWhf, vWh_sw, 512, 2048);
  prep(vWhb, vWh_sw + (size_t)512 * 2048, 512, 2048);
  prep(tWxf, tWxf_sw, 512, 2048);
  prep(tWxb, tWxb_sw, 512, 2048);
  prep(tWhf, tWh_sw, 512, 2048);
  prep(tWhb, tWh_sw + (size_t)512 * 2048, 512, 2048);
  prep(sqW1, W1_sw, 2048, 512);
  prep(rqW1, W1_sw + (size_t)2048 * 512, 2048, 512);

  hipMemsetAsync(flags, 0, (size_t)16 * 256 * 4, stream);

  size_t xgv_dir = (size_t)256 * 128 * 2048;
  size_t xgt_dir = (size_t)64 * 128 * 2048;
  k_proj<1024><<<256 * 8, 256, 0, stream>>>(vid, 256, 0, vWxf_sw, vbf, xg_vid);
  k_proj<1024><<<256 * 8, 256, 0, stream>>>(vid, 256, 1, vWxb_sw, vbb, xg_vid + xgv_dir);
  k_proj<512><<<64 * 8, 256, 0, stream>>>(txt, 64, 0, tWxf_sw, tbf, xg_txt);
  k_proj<512><<<64 * 8, 256, 0, stream>>>(txt, 64, 1, tWxb_sw, tbb, xg_txt + xgt_dir);

  k_rnn<<<128, 256, 0, stream>>>(xg_vid, xg_txt, vWh_sw, tWh_sw, hfrag, flags, feats);

  k_mlp<<<16, 256, 0, stream>>>(feats, W1_sw, sqb1, rqb1, h1);
  k_final<<<1, 256, 0, stream>>>(h1, sqW2, sqb2, rqW2, rqb2, labels, (float*)d_out);
}

// Round 3
// 6421.719 us; speedup vs baseline: 1.2334x; 1.2334x over previous
//
#include <hip/hip_runtime.h>
#include <hip/hip_bf16.h>

typedef __bf16 bf16_t;
typedef __bf16 bf16x8 __attribute__((ext_vector_type(8)));
typedef __bf16 bf16x4 __attribute__((ext_vector_type(4)));
typedef float f32x4 __attribute__((ext_vector_type(4)));

#define DEVI static __device__ __forceinline__

DEVI f32x4 mfma16(bf16x8 a, bf16x8 b, f32x4 c) {
  return __builtin_amdgcn_mfma_f32_16x16x32_bf16(a, b, c, 0, 0, 0);
}

DEVI float sigf(float x) { return 1.f / (1.f + __expf(-x)); }
DEVI float tanh_fast(float x) { return 2.f / (1.f + __expf(-2.f * x)) - 1.f; }

// ---------------------------------------------------------------------------
// Pre-swizzle weight matrix W [K,N] (f32 row-major) into B-fragment-major bf16:
// Wsw[kc][nt][lane][j] = W[kc*32 + (lane>>4)*8 + j][nt*16 + (lane&15)]
// ---------------------------------------------------------------------------
__global__ __launch_bounds__(256) void k_prep(const float* __restrict__ src,
                                              bf16_t* __restrict__ dst,
                                              int K, int N) {
  int gid = blockIdx.x * 256 + threadIdx.x;
  int total = (K / 32) * (N / 16) * 64;
  if (gid >= total) return;
  int l = gid & 63;
  int fi = gid >> 6;
  int NT = N >> 4;
  int nt = fi % NT;
  int kc = fi / NT;
  int row0 = kc * 32 + (l >> 4) * 8;
  int col = nt * 16 + (l & 15);
  bf16x8 v;
#pragma unroll
  for (int j = 0; j < 8; ++j) v[j] = (bf16_t)src[(size_t)(row0 + j) * N + col];
  *(bf16x8*)(dst + (size_t)gid * 8) = v;
}

// ---------------------------------------------------------------------------
// Input projection: xg[t] = x[:, t_eff, :] @ Wx + b  for one direction.
// Output xg in C-fragment-major layout:
//   xg[((t*8 + mtg)*128 + ntg)*64 + lane][r]  (bf16, r=0..3)
// ---------------------------------------------------------------------------
template <int KDIM>
__global__ __launch_bounds__(256) void k_proj(const float* __restrict__ x, int T,
                                              int dir,
                                              const bf16_t* __restrict__ Wsw,
                                              const float* __restrict__ bias,
                                              bf16_t* __restrict__ xg) {
  int chunk = blockIdx.x & 7;
  int t = blockIdx.x >> 3;
  int tt = dir ? (T - 1 - t) : t;
  int tid = threadIdx.x;
  int l = tid & 63, w = tid >> 6;
  int wr = w >> 1, wc = w & 1;
  int rl = l & 15, kl = (l >> 4) * 8;
  f32x4 acc[4][8];
#pragma unroll
  for (int mt = 0; mt < 4; ++mt)
#pragma unroll
    for (int nt = 0; nt < 8; ++nt) acc[mt][nt] = f32x4{0.f, 0.f, 0.f, 0.f};

  for (int kc = 0; kc < KDIM / 32; ++kc) {
    bf16x8 a[4];
#pragma unroll
    for (int mt = 0; mt < 4; ++mt) {
      int chain = wr * 64 + mt * 16 + rl;
      const float* p = x + ((size_t)chain * T + tt) * KDIM + kc * 32 + kl;
      float4 u = *(const float4*)p;
      float4 v = *(const float4*)(p + 4);
      bf16x8 av;
      av[0] = (bf16_t)u.x; av[1] = (bf16_t)u.y; av[2] = (bf16_t)u.z; av[3] = (bf16_t)u.w;
      av[4] = (bf16_t)v.x; av[5] = (bf16_t)v.y; av[6] = (bf16_t)v.z; av[7] = (bf16_t)v.w;
      a[mt] = av;
    }
#pragma unroll
    for (int nt = 0; nt < 8; ++nt) {
      int nt_g = chunk * 16 + wc * 8 + nt;
      bf16x8 b = *(const bf16x8*)(Wsw + ((size_t)(kc * 128 + nt_g) * 64 + l) * 8);
#pragma unroll
      for (int mt = 0; mt < 4; ++mt) acc[mt][nt] = mfma16(a[mt], b, acc[mt][nt]);
    }
  }

#pragma unroll
  for (int mt = 0; mt < 4; ++mt) {
    int mt_g = wr * 4 + mt;
#pragma unroll
    for (int nt = 0; nt < 8; ++nt) {
      int nt_g = chunk * 16 + wc * 8 + nt;
      float bv = bias[nt_g * 16 + rl];
      bf16x4 ov;
#pragma unroll
      for (int r = 0; r < 4; ++r) ov[r] = (bf16_t)(acc[mt][nt][r] + bv);
      *(bf16x4*)(xg + (((size_t)(t * 8 + mt_g) * 128 + nt_g) * 64 + l) * 4) = ov;
    }
  }
}

// ---------------------------------------------------------------------------
// Persistent recurrence kernel, v2 (minimal-coherence flag sync).
// Grid: 64 WGs x 256 thr. Group = (species, dir, chain-half): 8 groups x 8 WGs.
// Wave (wgi,w) -> jt = wgi*4+w: owns 16 hidden cols (jt*16..+16) x 4 gates x
// 64 chains (half). Wh slice (64 frags = 256 regs) register-resident.
// h per group: fragment-major parity buffers [2][kc=16][mt=4][lane=64][8] bf16
// (64KB each). Sync per step: WG leader does ONE release fence + flag add;
// consumers poll RELAXED then ONE acquire fence.
// ---------------------------------------------------------------------------
__global__ __launch_bounds__(256, 1) void k_rnn(
    const bf16_t* __restrict__ xg_vid, const bf16_t* __restrict__ xg_txt,
    const bf16_t* __restrict__ Wh_vid, const bf16_t* __restrict__ Wh_txt,
    bf16_t* __restrict__ hbuf, int* __restrict__ flags,
    bf16_t* __restrict__ feats) {
  int bid = blockIdx.x;
  int g = bid >> 3;            // group 0..7
  int wgi = bid & 7;           // WG within group
  int species = g >> 2, dir = (g >> 1) & 1, half = g & 1;
  int tid = threadIdx.x;
  int w = tid >> 6, l = tid & 63;
  int jt = wgi * 4 + w;        // hidden-col tile 0..31
  int rl = l & 15, lh = l >> 4;

  int NT = species ? 64 : 256;
  const bf16_t* xg = (species ? xg_txt : xg_vid) + (size_t)dir * NT * (128 * 2048);
  const bf16_t* Wh = (species ? Wh_txt : Wh_vid) + (size_t)dir * (512 * 2048);
  bf16_t* hb = hbuf + (size_t)g * 2 * 32768;
  int* flg = flags + g * 256;
  int colbase = species * 1024 + dir * 512;

  // Register-resident Wh slice: B[kc][gate].
  bf16x8 B[16][4];
#pragma unroll
  for (int kc = 0; kc < 16; ++kc)
#pragma unroll
    for (int gg = 0; gg < 4; ++gg)
      B[kc][gg] = *(const bf16x8*)(Wh + ((size_t)(kc * 128 + gg * 32 + jt) * 64 + l) * 8);

  float c[4][4];
#pragma unroll
  for (int mt = 0; mt < 4; ++mt)
#pragma unroll
    for (int r = 0; r < 4; ++r) c[mt][r] = 0.f;

  // h-store address components (hidden col j = jt*16 + rl)
  int jj = (jt & 1) * 16 + rl;     // j & 31
  int kc_w = jt >> 1;              // j >> 5
  int lane_hi = (jj >> 3) << 4;    // high lane bits from k-position
  int jp = jj & 7;                 // elem within 8

  for (int s = 0; s < NT; ++s) {
    // xg loads issued before the wait (independent of h).
    bf16x4 xv[4][4];
#pragma unroll
    for (int mt = 0; mt < 4; ++mt)
#pragma unroll
      for (int gg = 0; gg < 4; ++gg)
        xv[mt][gg] = *(const bf16x4*)(
            xg + (((size_t)(s * 8 + half * 4 + mt) * 128 + gg * 32 + jt) * 64 + l) * 4);

    if (s > 0) {
      const int* fl = flg + (s - 1);
      while (__hip_atomic_load(fl, __ATOMIC_RELAXED, __HIP_MEMORY_SCOPE_AGENT) < 8)
        __builtin_amdgcn_s_sleep(1);
      __builtin_amdgcn_fence(__ATOMIC_ACQUIRE, "agent");
    }

    f32x4 acc[4][4];
#pragma unroll
    for (int mt = 0; mt < 4; ++mt)
#pragma unroll
      for (int gg = 0; gg < 4; ++gg)
        acc[mt][gg] = f32x4{(float)xv[mt][gg][0], (float)xv[mt][gg][1],
                            (float)xv[mt][gg][2], (float)xv[mt][gg][3]};

    if (s > 0) {
      const bf16_t* hcur = hb + (size_t)(s & 1) * 32768;
#pragma unroll
      for (int kc = 0; kc < 16; ++kc) {
        bf16x8 a[4];
#pragma unroll
        for (int mt = 0; mt < 4; ++mt)
          a[mt] = *(const bf16x8*)(hcur + ((size_t)(kc * 4 + mt) * 64 + l) * 8);
#pragma unroll
        for (int gg = 0; gg < 4; ++gg)
#pragma unroll
          for (int mt = 0; mt < 4; ++mt)
            acc[mt][gg] = mfma16(a[mt], B[kc][gg], acc[mt][gg]);
      }
    }

    bf16_t* hnext = hb + (size_t)((s + 1) & 1) * 32768;
#pragma unroll
    for (int mt = 0; mt < 4; ++mt) {
#pragma unroll
      for (int r = 0; r < 4; ++r) {
        float iv = acc[mt][0][r], fv = acc[mt][1][r];
        float gv = acc[mt][2][r], ov = acc[mt][3][r];
        float cn = sigf(fv) * c[mt][r] + sigf(iv) * tanh_fast(gv);
        c[mt][r] = cn;
        float hn = sigf(ov) * tanh_fast(cn);
        int row = lh * 4 + r;                       // chain within 16-tile
        hnext[((size_t)(kc_w * 4 + mt) * 64 + (lane_hi + row)) * 8 + jp] = (bf16_t)hn;
        if (s == NT - 1) {
          int chain = half * 64 + mt * 16 + row;
          feats[(size_t)chain * 2048 + colbase + jt * 16 + rl] = (bf16_t)hn;
        }
      }
    }
    __syncthreads();  // drains each wave's vmcnt -> all WG h-stores are in L2
    if (tid == 0) {
      __builtin_amdgcn_fence(__ATOMIC_RELEASE, "agent");  // wbl2: flush to IF$
      __hip_atomic_fetch_add(flg + s, 1, __ATOMIC_RELAXED, __HIP_MEMORY_SCOPE_AGENT);
    }
  }
}

// ---------------------------------------------------------------------------
// h1[mlp] = relu(feats @ W1[mlp] + b1[mlp]) : [128,2048]x[2048,512]
// ---------------------------------------------------------------------------
__global__ __launch_bounds__(256) void k_mlp(const bf16_t* __restrict__ feats,
                                             const bf16_t* __restrict__ W1sw,
                                             const float* __restrict__ sqb1,
                                             const float* __restrict__ rqb1,
                                             float* __restrict__ h1) {
  int mlp = blockIdx.x >> 3, chunk = blockIdx.x & 7;
  const bf16_t* Wsw = W1sw + (size_t)mlp * (2048 * 512);
  const float* b1 = mlp ? rqb1 : sqb1;
  int tid = threadIdx.x;
  int l = tid & 63, w = tid >> 6;
  int rl = l & 15, kl = (l >> 4) * 8;
  f32x4 acc[2][4];
#pragma unroll
  for (int mt = 0; mt < 2; ++mt)
#pragma unroll
    for (int nt = 0; nt < 4; ++nt) acc[mt][nt] = f32x4{0.f, 0.f, 0.f, 0.f};

  for (int kc = 0; kc < 64; ++kc) {
    bf16x8 a[2];
#pragma unroll
    for (int mt = 0; mt < 2; ++mt) {
      int row = w * 32 + mt * 16 + rl;
      a[mt] = *(const bf16x8*)(feats + (size_t)row * 2048 + kc * 32 + kl);
    }
#pragma unroll
    for (int nt = 0; nt < 4; ++nt) {
      int nt_g = chunk * 4 + nt;
      bf16x8 b = *(const bf16x8*)(Wsw + ((size_t)(kc * 32 + nt_g) * 64 + l) * 8);
#pragma unroll
      for (int mt = 0; mt < 2; ++mt) acc[mt][nt] = mfma16(a[mt], b, acc[mt][nt]);
    }
  }

#pragma unroll
  for (int mt = 0; mt < 2; ++mt)
#pragma unroll
    for (int nt = 0; nt < 4; ++nt) {
      int col = (chunk * 4 + nt) * 16 + rl;
      float bv = b1[col];
#pragma unroll
      for (int r = 0; r < 4; ++r) {
        int row = w * 32 + mt * 16 + (l >> 4) * 4 + r;
        float v = acc[mt][nt][r] + bv;
        h1[(size_t)mlp * (128 * 512) + (size_t)row * 512 + col] = v > 0.f ? v : 0.f;
      }
    }
}

// ---------------------------------------------------------------------------
__global__ __launch_bounds__(256) void k_final(const float* __restrict__ h1,
                                               const float* __restrict__ sqW2,
                                               const float* __restrict__ sqb2,
                                               const float* __restrict__ rqW2,
                                               const float* __restrict__ rqb2,
                                               const int* __restrict__ labels,
                                               float* __restrict__ out) {
  __shared__ float sc[128][2];
  int tid = threadIdx.x;
  int row = tid >> 1, m = tid & 1;
  const float* hp = h1 + ((size_t)m * 128 + row) * 512;
  const float* w2 = m ? rqW2 : sqW2;
  float s = m ? *rqb2 : *sqb2;
  for (int k = 0; k < 512; ++k) s += hp[k] * w2[k];
  sc[row][m] = s;
  __syncthreads();
  if (tid < 16) {
    float acc = 0.f;
    for (int i = 0; i < 8; ++i) {
      int r = tid * 8 + i;
      acc += (labels[r] <= 3) ? sc[r][0] : sc[r][1];
    }
    acc *= (1.f / 8.f);
    out[tid] = 1.f / (1.f + __expf(-acc));
  }
}

// ---------------------------------------------------------------------------
extern "C" void kernel_launch(void* const* d_in, const int* in_sizes, int n_in,
                              void* d_out, int out_size, void* d_ws, size_t ws_size,
                              hipStream_t stream) {
  const float* vid  = (const float*)d_in[0];
  const float* txt  = (const float*)d_in[1];
  const int* labels = (const int*)d_in[2];
  const float* vWxf = (const float*)d_in[3];
  const float* vWhf = (const float*)d_in[4];
  const float* vbf  = (const float*)d_in[5];
  const float* vWxb = (const float*)d_in[6];
  const float* vWhb = (const float*)d_in[7];
  const float* vbb  = (const float*)d_in[8];
  const float* tWxf = (const float*)d_in[9];
  const float* tWhf = (const float*)d_in[10];
  const float* tbf  = (const float*)d_in[11];
  const float* tWxb = (const float*)d_in[12];
  const float* tWhb = (const float*)d_in[13];
  const float* tbb  = (const float*)d_in[14];
  const float* sqW1 = (const float*)d_in[15];
  const float* sqb1 = (const float*)d_in[16];
  const float* sqW2 = (const float*)d_in[17];
  const float* sqb2 = (const float*)d_in[18];
  const float* rqW1 = (const float*)d_in[19];
  const float* rqb1 = (const float*)d_in[20];
  const float* rqW2 = (const float*)d_in[21];
  const float* rqb2 = (const float*)d_in[22];

  char* p = (char*)d_ws;
  auto alloc = [&](size_t bytes) {
    char* r = p;
    p += (bytes + 255) & ~(size_t)255;
    return r;
  };
  bf16_t* vWxf_sw = (bf16_t*)alloc((size_t)1024 * 2048 * 2);
  bf16_t* vWxb_sw = (bf16_t*)alloc((size_t)1024 * 2048 * 2);
  bf16_t* vWh_sw  = (bf16_t*)alloc((size_t)2 * 512 * 2048 * 2);  // [dir]
  bf16_t* tWxf_sw = (bf16_t*)alloc((size_t)512 * 2048 * 2);
  bf16_t* tWxb_sw = (bf16_t*)alloc((size_t)512 * 2048 * 2);
  bf16_t* tWh_sw  = (bf16_t*)alloc((size_t)2 * 512 * 2048 * 2);  // [dir]
  bf16_t* W1_sw   = (bf16_t*)alloc((size_t)2 * 2048 * 512 * 2);  // [mlp]
  bf16_t* xg_vid  = (bf16_t*)alloc((size_t)2 * 256 * 128 * 2048 * 2);
  bf16_t* xg_txt  = (bf16_t*)alloc((size_t)2 * 64 * 128 * 2048 * 2);
  bf16_t* hbuf    = (bf16_t*)alloc((size_t)8 * 2 * 32768 * 2);   // [grp][parity]
  int*    flags   = (int*)alloc((size_t)8 * 256 * 4);
  bf16_t* feats   = (bf16_t*)alloc((size_t)128 * 2048 * 2);
  float*  h1      = (float*)alloc((size_t)2 * 128 * 512 * 4);
  (void)ws_size; (void)in_sizes; (void)n_in; (void)out_size;

  auto prep = [&](const float* s, bf16_t* d, int K, int N) {
    int total = (K / 32) * (N / 16) * 64;
    k_prep<<<(total + 255) / 256, 256, 0, stream>>>(s, d, K, N);
  };
  prep(vWxf, vWxf_sw, 1024, 2048);
  prep(vWxb, vWxb_sw, 1024, 2048);
  prep(vWhf, vWh_sw, 512, 2048);
  prep(vWhb, vWh_sw + (size_t)512 * 2048, 512, 2048);
  prep(tWxf, tWxf_sw, 512, 2048);
  prep(tWxb, tWxb_sw, 512, 2048);
  prep(tWhf, tWh_sw, 512, 2048);
  prep(tWhb, tWh_sw + (size_t)512 * 2048, 512, 2048);
  prep(sqW1, W1_sw, 2048, 512);
  prep(rqW1, W1_sw + (size_t)2048 * 512, 2048, 512);

  hipMemsetAsync(flags, 0, (size_t)8 * 256 * 4, stream);

  size_t xgv_dir = (size_t)256 * 128 * 2048;
  size_t xgt_dir = (size_t)64 * 128 * 2048;
  k_proj<1024><<<256 * 8, 256, 0, stream>>>(vid, 256, 0, vWxf_sw, vbf, xg_vid);
  k_proj<1024><<<256 * 8, 256, 0, stream>>>(vid, 256, 1, vWxb_sw, vbb, xg_vid + xgv_dir);
  k_proj<512><<<64 * 8, 256, 0, stream>>>(txt, 64, 0, tWxf_sw, tbf, xg_txt);
  k_proj<512><<<64 * 8, 256, 0, stream>>>(txt, 64, 1, tWxb_sw, tbb, xg_txt + xgt_dir);

  k_rnn<<<64, 256, 0, stream>>>(xg_vid, xg_txt, vWh_sw, tWh_sw, hbuf, flags, feats);

  k_mlp<<<16, 256, 0, stream>>>(feats, W1_sw, sqb1, rqb1, h1);
  k_final<<<1, 256, 0, stream>>>(h1, sqW2, sqb2, rqW2, rqb2, labels, (float*)d_out);
}

// Round 4
// 2862.730 us; speedup vs baseline: 2.7668x; 2.2432x over previous
//
#include <hip/hip_runtime.h>
#include <hip/hip_bf16.h>

typedef __bf16 bf16_t;
typedef __bf16 bf16x8 __attribute__((ext_vector_type(8)));
typedef __bf16 bf16x4 __attribute__((ext_vector_type(4)));
typedef float f32x4 __attribute__((ext_vector_type(4)));

#define DEVI static __device__ __forceinline__

DEVI f32x4 mfma16(bf16x8 a, bf16x8 b, f32x4 c) {
  return __builtin_amdgcn_mfma_f32_16x16x32_bf16(a, b, c, 0, 0, 0);
}

DEVI float sigf(float x) { return 1.f / (1.f + __expf(-x)); }
DEVI float tanh_fast(float x) { return 2.f / (1.f + __expf(-2.f * x)) - 1.f; }

// ---------------------------------------------------------------------------
// Pre-swizzle weight matrix W [K,N] (f32 row-major) into B-fragment-major bf16:
// Wsw[kc][nt][lane][j] = W[kc*32 + (lane>>4)*8 + j][nt*16 + (lane&15)]
// ---------------------------------------------------------------------------
__global__ __launch_bounds__(256) void k_prep(const float* __restrict__ src,
                                              bf16_t* __restrict__ dst,
                                              int K, int N) {
  int gid = blockIdx.x * 256 + threadIdx.x;
  int total = (K / 32) * (N / 16) * 64;
  if (gid >= total) return;
  int l = gid & 63;
  int fi = gid >> 6;
  int NT = N >> 4;
  int nt = fi % NT;
  int kc = fi / NT;
  int row0 = kc * 32 + (l >> 4) * 8;
  int col = nt * 16 + (l & 15);
  bf16x8 v;
#pragma unroll
  for (int j = 0; j < 8; ++j) v[j] = (bf16_t)src[(size_t)(row0 + j) * N + col];
  *(bf16x8*)(dst + (size_t)gid * 8) = v;
}

// ---------------------------------------------------------------------------
// Input projection: xg[t] = x[:, t_eff, :] @ Wx + b  for one direction.
// Output xg in C-fragment-major layout:
//   xg[((t*8 + mtg)*128 + ntg)*64 + lane][r]  (bf16, r=0..3)
// ---------------------------------------------------------------------------
template <int KDIM>
__global__ __launch_bounds__(256) void k_proj(const float* __restrict__ x, int T,
                                              int dir,
                                              const bf16_t* __restrict__ Wsw,
                                              const float* __restrict__ bias,
                                              bf16_t* __restrict__ xg) {
  int chunk = blockIdx.x & 7;
  int t = blockIdx.x >> 3;
  int tt = dir ? (T - 1 - t) : t;
  int tid = threadIdx.x;
  int l = tid & 63, w = tid >> 6;
  int wr = w >> 1, wc = w & 1;
  int rl = l & 15, kl = (l >> 4) * 8;
  f32x4 acc[4][8];
#pragma unroll
  for (int mt = 0; mt < 4; ++mt)
#pragma unroll
    for (int nt = 0; nt < 8; ++nt) acc[mt][nt] = f32x4{0.f, 0.f, 0.f, 0.f};

  for (int kc = 0; kc < KDIM / 32; ++kc) {
    bf16x8 a[4];
#pragma unroll
    for (int mt = 0; mt < 4; ++mt) {
      int chain = wr * 64 + mt * 16 + rl;
      const float* p = x + ((size_t)chain * T + tt) * KDIM + kc * 32 + kl;
      float4 u = *(const float4*)p;
      float4 v = *(const float4*)(p + 4);
      bf16x8 av;
      av[0] = (bf16_t)u.x; av[1] = (bf16_t)u.y; av[2] = (bf16_t)u.z; av[3] = (bf16_t)u.w;
      av[4] = (bf16_t)v.x; av[5] = (bf16_t)v.y; av[6] = (bf16_t)v.z; av[7] = (bf16_t)v.w;
      a[mt] = av;
    }
#pragma unroll
    for (int nt = 0; nt < 8; ++nt) {
      int nt_g = chunk * 16 + wc * 8 + nt;
      bf16x8 b = *(const bf16x8*)(Wsw + ((size_t)(kc * 128 + nt_g) * 64 + l) * 8);
#pragma unroll
      for (int mt = 0; mt < 4; ++mt) acc[mt][nt] = mfma16(a[mt], b, acc[mt][nt]);
    }
  }

#pragma unroll
  for (int mt = 0; mt < 4; ++mt) {
    int mt_g = wr * 4 + mt;
#pragma unroll
    for (int nt = 0; nt < 8; ++nt) {
      int nt_g = chunk * 16 + wc * 8 + nt;
      float bv = bias[nt_g * 16 + rl];
      bf16x4 ov;
#pragma unroll
      for (int r = 0; r < 4; ++r) ov[r] = (bf16_t)(acc[mt][nt][r] + bv);
      *(bf16x4*)(xg + (((size_t)(t * 8 + mt_g) * 128 + nt_g) * 64 + l) * 4) = ov;
    }
  }
}

// ---------------------------------------------------------------------------
// Persistent recurrence kernel, v3: fence-free IF$ exchange.
// Grid: 128 WGs x 256 thr = 8 groups (species,dir,half) x 16 WGs.
// Wave slot = wgi*4+w -> jt = slot>>1 (16 hidden cols), mth = slot&1
// (which 32-chain block of the 64-chain half). Wave computes 2 mt-tiles x
// 4 gates x 16 kc = 128 MFMAs/step; Wh slice (64 frags) register-resident.
// h exchange: relaxed AGENT atomics only (sc0 sc1 -> IF$-coherent, no
// buffer_inv/wbl2). Producer: stores -> __syncthreads (vmcnt drain) ->
// leader relaxed flag add. Consumer: relaxed poll -> compiler barrier ->
// atomic h loads (HW issues VMEM in program order after the branch).
// ---------------------------------------------------------------------------
__global__ __launch_bounds__(256, 1) void k_rnn(
    const bf16_t* __restrict__ xg_vid, const bf16_t* __restrict__ xg_txt,
    const bf16_t* __restrict__ Wh_vid, const bf16_t* __restrict__ Wh_txt,
    bf16_t* __restrict__ hbuf, int* __restrict__ flags,
    bf16_t* __restrict__ feats) {
  int bid = blockIdx.x;
  int g = bid >> 4;            // group 0..7
  int wgi = bid & 15;          // WG within group
  int species = g >> 2, dir = (g >> 1) & 1, half = g & 1;
  int tid = threadIdx.x;
  int w = tid >> 6, l = tid & 63;
  int slot = wgi * 4 + w;      // 0..63
  int jt = slot >> 1;          // hidden-col tile 0..31
  int mth = slot & 1;          // 32-chain block within the half
  int rl = l & 15, lh = l >> 4;

  int NT = species ? 64 : 256;
  const bf16_t* xg = (species ? xg_txt : xg_vid) + (size_t)dir * NT * (128 * 2048);
  const bf16_t* Wh = (species ? Wh_txt : Wh_vid) + (size_t)dir * (512 * 2048);
  bf16_t* hb = hbuf + (size_t)g * 2 * 32768;
  int* flg = flags + g * 256;
  int colbase = species * 1024 + dir * 512;

  // Register-resident Wh slice: B[kc][gate] for this jt.
  bf16x8 B[16][4];
#pragma unroll
  for (int kc = 0; kc < 16; ++kc)
#pragma unroll
    for (int gg = 0; gg < 4; ++gg)
      B[kc][gg] = *(const bf16x8*)(Wh + ((size_t)(kc * 128 + gg * 32 + jt) * 64 + l) * 8);

  float c[2][4];
#pragma unroll
  for (int mt = 0; mt < 2; ++mt)
#pragma unroll
    for (int r = 0; r < 4; ++r) c[mt][r] = 0.f;

  // h-store address components (hidden col j = jt*16 + rl)
  int jj = (jt & 1) * 16 + rl;     // j & 31
  int kc_w = jt >> 1;              // j >> 5
  int lane_hi = (jj >> 3) << 4;    // high lane bits from k-position
  int jp = jj & 7;                 // elem within 8

  for (int s = 0; s < NT; ++s) {
    // xg loads issued before the wait (independent of h, normal cached path).
    bf16x4 xv[2][4];
#pragma unroll
    for (int mt = 0; mt < 2; ++mt) {
      int mtt = mth * 2 + mt;
#pragma unroll
      for (int gg = 0; gg < 4; ++gg)
        xv[mt][gg] = *(const bf16x4*)(
            xg + (((size_t)(s * 8 + half * 4 + mtt) * 128 + gg * 32 + jt) * 64 + l) * 4);
    }

    f32x4 acc[2][4];
#pragma unroll
    for (int mt = 0; mt < 2; ++mt)
#pragma unroll
      for (int gg = 0; gg < 4; ++gg)
        acc[mt][gg] = f32x4{(float)xv[mt][gg][0], (float)xv[mt][gg][1],
                            (float)xv[mt][gg][2], (float)xv[mt][gg][3]};

    if (s > 0) {
      const int* fl = flg + (s - 1);
      while (__hip_atomic_load(fl, __ATOMIC_RELAXED, __HIP_MEMORY_SCOPE_AGENT) < 16)
        __builtin_amdgcn_s_sleep(1);
      asm volatile("" ::: "memory");  // compiler barrier: keep h loads below

      const bf16_t* hcur = hb + (size_t)(s & 1) * 32768;
      // Load all A-fragments coherently (IF$), then MFMA.
      bf16x8 af[16][2];
#pragma unroll
      for (int kc = 0; kc < 16; ++kc) {
#pragma unroll
        for (int mt = 0; mt < 2; ++mt) {
          int mtt = mth * 2 + mt;
          const unsigned long long* ap = (const unsigned long long*)(
              hcur + ((size_t)(kc * 4 + mtt) * 64 + l) * 8);
          unsigned long long lo =
              __hip_atomic_load(ap, __ATOMIC_RELAXED, __HIP_MEMORY_SCOPE_AGENT);
          unsigned long long hi =
              __hip_atomic_load(ap + 1, __ATOMIC_RELAXED, __HIP_MEMORY_SCOPE_AGENT);
          union { unsigned long long u[2]; bf16x8 v; } cvt;
          cvt.u[0] = lo; cvt.u[1] = hi;
          af[kc][mt] = cvt.v;
        }
      }
#pragma unroll
      for (int kc = 0; kc < 16; ++kc)
#pragma unroll
        for (int gg = 0; gg < 4; ++gg)
#pragma unroll
          for (int mt = 0; mt < 2; ++mt)
            acc[mt][gg] = mfma16(af[kc][mt], B[kc][gg], acc[mt][gg]);
    }

    bf16_t* hnext = hb + (size_t)((s + 1) & 1) * 32768;
#pragma unroll
    for (int mt = 0; mt < 2; ++mt) {
      int mtt = mth * 2 + mt;
#pragma unroll
      for (int r = 0; r < 4; ++r) {
        float iv = acc[mt][0][r], fv = acc[mt][1][r];
        float gv = acc[mt][2][r], ov = acc[mt][3][r];
        float cn = sigf(fv) * c[mt][r] + sigf(iv) * tanh_fast(gv);
        c[mt][r] = cn;
        float hn = sigf(ov) * tanh_fast(cn);
        int row = lh * 4 + r;
        // coherent write-through store (IF$), no fence needed
        __hip_atomic_store(
            &hnext[((size_t)(kc_w * 4 + mtt) * 64 + (lane_hi + row)) * 8 + jp],
            (bf16_t)hn, __ATOMIC_RELAXED, __HIP_MEMORY_SCOPE_AGENT);
        if (s == NT - 1) {
          int chain = half * 64 + mtt * 16 + row;
          feats[(size_t)chain * 2048 + colbase + jt * 16 + rl] = (bf16_t)hn;
        }
      }
    }
    __syncthreads();  // drains each wave's vmcnt -> all WG h-stores at IF$
    if (tid == 0)
      __hip_atomic_fetch_add(flg + s, 1, __ATOMIC_RELAXED, __HIP_MEMORY_SCOPE_AGENT);
  }
}

// ---------------------------------------------------------------------------
// h1[mlp] = relu(feats @ W1[mlp] + b1[mlp]) : [128,2048]x[2048,512]
// ---------------------------------------------------------------------------
__global__ __launch_bounds__(256) void k_mlp(const bf16_t* __restrict__ feats,
                                             const bf16_t* __restrict__ W1sw,
                                             const float* __restrict__ sqb1,
                                             const float* __restrict__ rqb1,
                                             float* __restrict__ h1) {
  int mlp = blockIdx.x >> 3, chunk = blockIdx.x & 7;
  const bf16_t* Wsw = W1sw + (size_t)mlp * (2048 * 512);
  const float* b1 = mlp ? rqb1 : sqb1;
  int tid = threadIdx.x;
  int l = tid & 63, w = tid >> 6;
  int rl = l & 15, kl = (l >> 4) * 8;
  f32x4 acc[2][4];
#pragma unroll
  for (int mt = 0; mt < 2; ++mt)
#pragma unroll
    for (int nt = 0; nt < 4; ++nt) acc[mt][nt] = f32x4{0.f, 0.f, 0.f, 0.f};

  for (int kc = 0; kc < 64; ++kc) {
    bf16x8 a[2];
#pragma unroll
    for (int mt = 0; mt < 2; ++mt) {
      int row = w * 32 + mt * 16 + rl;
      a[mt] = *(const bf16x8*)(feats + (size_t)row * 2048 + kc * 32 + kl);
    }
#pragma unroll
    for (int nt = 0; nt < 4; ++nt) {
      int nt_g = chunk * 4 + nt;
      bf16x8 b = *(const bf16x8*)(Wsw + ((size_t)(kc * 32 + nt_g) * 64 + l) * 8);
#pragma unroll
      for (int mt = 0; mt < 2; ++mt) acc[mt][nt] = mfma16(a[mt], b, acc[mt][nt]);
    }
  }

#pragma unroll
  for (int mt = 0; mt < 2; ++mt)
#pragma unroll
    for (int nt = 0; nt < 4; ++nt) {
      int col = (chunk * 4 + nt) * 16 + rl;
      float bv = b1[col];
#pragma unroll
      for (int r = 0; r < 4; ++r) {
        int row = w * 32 + mt * 16 + (l >> 4) * 4 + r;
        float v = acc[mt][nt][r] + bv;
        h1[(size_t)mlp * (128 * 512) + (size_t)row * 512 + col] = v > 0.f ? v : 0.f;
      }
    }
}

// ---------------------------------------------------------------------------
__global__ __launch_bounds__(256) void k_final(const float* __restrict__ h1,
                                               const float* __restrict__ sqW2,
                                               const float* __restrict__ sqb2,
                                               const float* __restrict__ rqW2,
                                               const float* __restrict__ rqb2,
                                               const int* __restrict__ labels,
                                               float* __restrict__ out) {
  __shared__ float sc[128][2];
  int tid = threadIdx.x;
  int row = tid >> 1, m = tid & 1;
  const float* hp = h1 + ((size_t)m * 128 + row) * 512;
  const float* w2 = m ? rqW2 : sqW2;
  float s = m ? *rqb2 : *sqb2;
  for (int k = 0; k < 512; ++k) s += hp[k] * w2[k];
  sc[row][m] = s;
  __syncthreads();
  if (tid < 16) {
    float acc = 0.f;
    for (int i = 0; i < 8; ++i) {
      int r = tid * 8 + i;
      acc += (labels[r] <= 3) ? sc[r][0] : sc[r][1];
    }
    acc *= (1.f / 8.f);
    out[tid] = 1.f / (1.f + __expf(-acc));
  }
}

// ---------------------------------------------------------------------------
extern "C" void kernel_launch(void* const* d_in, const int* in_sizes, int n_in,
                              void* d_out, int out_size, void* d_ws, size_t ws_size,
                              hipStream_t stream) {
  const float* vid  = (const float*)d_in[0];
  const float* txt  = (const float*)d_in[1];
  const int* labels = (const int*)d_in[2];
  const float* vWxf = (const float*)d_in[3];
  const float* vWhf = (const float*)d_in[4];
  const float* vbf  = (const float*)d_in[5];
  const float* vWxb = (const float*)d_in[6];
  const float* vWhb = (const float*)d_in[7];
  const float* vbb  = (const float*)d_in[8];
  const float* tWxf = (const float*)d_in[9];
  const float* tWhf = (const float*)d_in[10];
  const float* tbf  = (const float*)d_in[11];
  const float* tWxb = (const float*)d_in[12];
  const float* tWhb = (const float*)d_in[13];
  const float* tbb  = (const float*)d_in[14];
  const float* sqW1 = (const float*)d_in[15];
  const float* sqb1 = (const float*)d_in[16];
  const float* sqW2 = (const float*)d_in[17];
  const float* sqb2 = (const float*)d_in[18];
  const float* rqW1 = (const float*)d_in[19];
  const float* rqb1 = (const float*)d_in[20];
  const float* rqW2 = (const float*)d_in[21];
  const float* rqb2 = (const float*)d_in[22];

  char* p = (char*)d_ws;
  auto alloc = [&](size_t bytes) {
    char* r = p;
    p += (bytes + 255) & ~(size_t)255;
    return r;
  };
  bf16_t* vWxf_sw = (bf16_t*)alloc((size_t)1024 * 2048 * 2);
  bf16_t* vWxb_sw = (bf16_t*)alloc((size_t)1024 * 2048 * 2);
  bf16_t* vWh_sw  = (bf16_t*)alloc((size_t)2 * 512 * 2048 * 2);  // [dir]
  bf16_t* tWxf_sw = (bf16_t*)alloc((size_t)512 * 2048 * 2);
  bf16_t* tWxb_sw = (bf16_t*)alloc((size_t)512 * 2048 * 2);
  bf16_t* tWh_sw  = (bf16_t*)alloc((size_t)2 * 512 * 2048 * 2);  // [dir]
  bf16_t* W1_sw   = (bf16_t*)alloc((size_t)2 * 2048 * 512 * 2);  // [mlp]
  bf16_t* xg_vid  = (bf16_t*)alloc((size_t)2 * 256 * 128 * 2048 * 2);
  bf16_t* xg_txt  = (bf16_t*)alloc((size_t)2 * 64 * 128 * 2048 * 2);
  bf16_t* hbuf    = (bf16_t*)alloc((size_t)8 * 2 * 32768 * 2);   // [grp][parity]
  int*    flags   = (int*)alloc((size_t)8 * 256 * 4);
  bf16_t* feats   = (bf16_t*)alloc((size_t)128 * 2048 * 2);
  float*  h1      = (float*)alloc((size_t)2 * 128 * 512 * 4);
  (void)ws_size; (void)in_sizes; (void)n_in; (void)out_size;

  auto prep = [&](const float* s, bf16_t* d, int K, int N) {
    int total = (K / 32) * (N / 16) * 64;
    k_prep<<<(total + 255) / 256, 256, 0, stream>>>(s, d, K, N);
  };
  prep(vWxf, vWxf_sw, 1024, 2048);
  prep(vWxb, vWxb_sw, 1024, 2048);
  prep(vWhf, vWh_sw, 512, 2048);
  prep(vWhb, vWh_sw + (size_t)512 * 2048, 512, 2048);
  prep(tWxf, tWxf_sw, 512, 2048);
  prep(tWxb, tWxb_sw, 512, 2048);
  prep(tWhf, tWh_sw, 512, 2048);
  prep(tWhb, tWh_sw + (size_t)512 * 2048, 512, 2048);
  prep(sqW1, W1_sw, 2048, 512);
  prep(rqW1, W1_sw + (size_t)2048 * 512, 2048, 512);

  hipMemsetAsync(flags, 0, (size_t)8 * 256 * 4, stream);

  size_t xgv_dir = (size_t)256 * 128 * 2048;
  size_t xgt_dir = (size_t)64 * 128 * 2048;
  k_proj<1024><<<256 * 8, 256, 0, stream>>>(vid, 256, 0, vWxf_sw, vbf, xg_vid);
  k_proj<1024><<<256 * 8, 256, 0, stream>>>(vid, 256, 1, vWxb_sw, vbb, xg_vid + xgv_dir);
  k_proj<512><<<64 * 8, 256, 0, stream>>>(txt, 64, 0, tWxf_sw, tbf, xg_txt);
  k_proj<512><<<64 * 8, 256, 0, stream>>>(txt, 64, 1, tWxb_sw, tbb, xg_txt + xgt_dir);

  k_rnn<<<128, 256, 0, stream>>>(xg_vid, xg_txt, vWh_sw, tWh_sw, hbuf, flags, feats);

  k_mlp<<<16, 256, 0, stream>>>(feats, W1_sw, sqb1, rqb1, h1);
  k_final<<<1, 256, 0, stream>>>(h1, sqW2, sqb2, rqW2, rqb2, labels, (float*)d_out);
}